// Round 5
// baseline (4183.439 us; speedup 1.0000x reference)
//
#include <hip/hip_runtime.h>
#include <stdint.h>

typedef unsigned int u32;
typedef unsigned long long u64;
typedef __attribute__((ext_vector_type(8))) short bf16x8;
typedef __attribute__((ext_vector_type(4))) float f32x4;
typedef __attribute__((ext_vector_type(4))) int i32x4;
typedef __attribute__((ext_vector_type(2))) int i32x2;

#define DEV static __device__ __forceinline__

DEV short f2bf(float f){ u32 u=__float_as_uint(f); return (short)((u + 0x7fffu + ((u>>16)&1u))>>16); }
DEV float bf2f(short s){ return __uint_as_float(((u32)(unsigned short)s)<<16); }
DEV float sig_p(float x){ return 1.f/(1.f+expf(-x)); }
DEV float tanh_fast(float x){ float e=__expf(2.f*x); return 1.f-2.f/(e+1.f); }

// relaxed agent-scope (LLC-coherent) accessors
DEV u32  cohl4(const u32* p){ return __hip_atomic_load(p, __ATOMIC_RELAXED, __HIP_MEMORY_SCOPE_AGENT); }
DEV void cohs4(u32* p, u32 v){ __hip_atomic_store(p, v, __ATOMIC_RELAXED, __HIP_MEMORY_SCOPE_AGENT); }
DEV u64  cohl8(const void* p){ return __hip_atomic_load((const u64*)p, __ATOMIC_RELAXED, __HIP_MEMORY_SCOPE_AGENT); }
DEV float cohlf(const float* p){ return __hip_atomic_load(p, __ATOMIC_RELAXED, __HIP_MEMORY_SCOPE_AGENT); }
DEV void cohsf(float* p, float v){ __hip_atomic_store(p, v, __ATOMIC_RELAXED, __HIP_MEMORY_SCOPE_AGENT); }
// busy poll: dependent LLC load self-paces the loop (~500 cyc/iter)
DEV void pollslot(const u32* s, u32 tgt){
  while (cohl4(s) < tgt) {}
}
// filler spin: keep CU busy (DVFS) until done-flag reaches 128
DEV void filler_spin(const u32* done){
  float x = (float)threadIdx.x;
  while (cohl4(done) < 128u){
#pragma unroll
    for (int i=0;i<128;++i) x = __builtin_fmaf(x, 1.0000001f, 0.1f);
    asm volatile("" :: "v"(x));
  }
}

// ---------------- convert / transpose kernels ----------------

__global__ void cvt1d(const float* __restrict__ in, short* __restrict__ out, int n){
  int i = blockIdx.x*256 + threadIdx.x;
  if (i < n) out[i] = f2bf(in[i]);
}

// in f32 [R][C] -> out bf16 [Cpad][R]
__global__ void tconv(const float* __restrict__ in, short* __restrict__ out, int R, int C, int Cpad){
  __shared__ float t[32][33];
  int tx = threadIdx.x, ty = threadIdx.y;
  int c0 = blockIdx.x*32, r0 = blockIdx.y*32;
#pragma unroll
  for (int j=0;j<4;++j){
    int r = r0 + ty + 8*j, c = c0 + tx;
    t[ty+8*j][tx] = (c < C) ? in[(size_t)r*C + c] : 0.f;
  }
  __syncthreads();
#pragma unroll
  for (int j=0;j<4;++j){
    int oc = c0 + ty + 8*j;
    out[(size_t)oc*R + r0 + tx] = f2bf(t[tx][ty+8*j]);
  }
}

// batched transpose: in bf16 [NB][Dd][32] -> out bf16 [NB*32][Dd]
__global__ void btrans(const short* __restrict__ in, short* __restrict__ out, int Dd){
  __shared__ short t[32][33];
  int tx = threadIdx.x, ty = threadIdx.y;
  int d0 = blockIdx.x*32, s = blockIdx.y;
#pragma unroll
  for (int j=0;j<4;++j)
    t[ty+8*j][tx] = in[((size_t)s*Dd + d0 + ty + 8*j)*32 + tx];
  __syncthreads();
#pragma unroll
  for (int j=0;j<4;++j)
    out[((size_t)(s*32 + ty + 8*j))*Dd + d0 + tx] = t[tx][ty+8*j];
}

// [s][1536][32] -> [b][1536][128]
__global__ void etrans(const short* __restrict__ in, short* __restrict__ out){
  __shared__ short t[128][33];
  int c = blockIdx.x, tid = threadIdx.x;
#pragma unroll
  for (int i=0;i<16;++i){
    int idx = tid + i*256;
    t[idx>>5][idx&31] = in[((size_t)(idx>>5)*1536 + c)*32 + (idx&31)];
  }
  __syncthreads();
#pragma unroll
  for (int i=0;i<16;++i){
    int idx = tid + i*256;
    out[((size_t)(idx>>7)*1536 + c)*128 + (idx&127)] = t[idx&127][idx>>7];
  }
}

__global__ void embed_k(const int* __restrict__ tok, const float* __restrict__ emb, short* __restrict__ X){
  int row = blockIdx.x;               // (s,b)
  int s = row >> 5, b = row & 31;
  int tv = tok[b*128 + s];
  X[(size_t)row*256 + threadIdx.x] = f2bf(emb[(size_t)tv*256 + threadIdx.x]);
}

// ---------------- MFMA GEMM  C = A[M,K] * BT[Npad][K] ----------------
template<int MODE>
__global__ __launch_bounds__(256) void gemm_k(
  const short* __restrict__ A, const short* __restrict__ BT,
  const float* __restrict__ bias, void* __restrict__ outp,
  float* __restrict__ psum, int Nreal, int K, int Ntot)
{
  const int m0 = blockIdx.y * 128, n0 = blockIdx.x * 128;
  const int tid = threadIdx.x, l = tid & 63, wv = tid >> 6;
  const int wm = wv >> 1, wn = wv & 1;
  __shared__ __align__(16) short As[128*64];
  __shared__ __align__(16) short Bs[128*64];
  f32x4 acc[4][4];
#pragma unroll
  for (int i=0;i<4;++i)
#pragma unroll
    for (int j=0;j<4;++j) acc[i][j] = (f32x4){0.f,0.f,0.f,0.f};

  const int nkb = K >> 6;
  for (int kb=0; kb<nkb; ++kb){
#pragma unroll
    for (int i=0;i<4;++i){
      int si = tid + i*256;
      int row = si >> 3, seg = si & 7;
      u32 off = (u32)(row*128 + seg*16) ^ (u32)((row&7)<<4);
      *(i32x4*)((char*)As + off) = *(const i32x4*)(A + (size_t)(m0+row)*K + kb*64 + seg*8);
      *(i32x4*)((char*)Bs + off) = *(const i32x4*)(BT + (size_t)(n0+row)*K + kb*64 + seg*8);
    }
    __syncthreads();
#pragma unroll
    for (int kt=0; kt<2; ++kt){
      bf16x8 af[4], bfv[4];
      int seg = kt*4 + (l>>4);
#pragma unroll
      for (int f=0; f<4; ++f){
        int ra = wm*64 + f*16 + (l&15);
        af[f]  = *(const bf16x8*)((char*)As + (((u32)(ra*128 + seg*16)) ^ ((u32)(ra&7)<<4)));
        int rb = wn*64 + f*16 + (l&15);
        bfv[f] = *(const bf16x8*)((char*)Bs + (((u32)(rb*128 + seg*16)) ^ ((u32)(rb&7)<<4)));
      }
#pragma unroll
      for (int mf=0; mf<4; ++mf)
#pragma unroll
        for (int nf=0; nf<4; ++nf)
          acc[mf][nf] = __builtin_amdgcn_mfma_f32_16x16x32_bf16(af[mf], bfv[nf], acc[mf][nf], 0,0,0);
    }
    __syncthreads();
  }

  if (MODE == 1){
    short* oT = (short*)outp;
#pragma unroll
    for (int mf=0; mf<4; ++mf){
      int r0 = m0 + wm*64 + mf*16 + ((l>>4)<<2);
      int s = r0 >> 5, b0 = r0 & 31;
#pragma unroll
      for (int nf=0; nf<4; ++nf){
        int col = n0 + wn*64 + nf*16 + (l&15);
        float bv = bias ? bias[col] : 0.f;
        short tmp[4];
#pragma unroll
        for (int j=0;j<4;++j) tmp[j] = f2bf(acc[mf][nf][j] + bv);
        *(i32x2*)(oT + ((size_t)s*Ntot + col)*32 + b0) = *(i32x2*)tmp;
      }
    }
  } else if (MODE == 3){
    short* o = (short*)outp;
#pragma unroll
    for (int mf=0; mf<4; ++mf){
      int r0 = m0 + wm*64 + mf*16 + ((l>>4)<<2);
#pragma unroll
      for (int nf=0; nf<4; ++nf){
        int col = n0 + wn*64 + nf*16 + (l&15);
        if (col < Nreal){
          float bv = bias ? bias[col] : 0.f;
#pragma unroll
          for (int j=0;j<4;++j) o[(size_t)(r0+j)*Nreal + col] = f2bf(acc[mf][nf][j] + bv);
        }
      }
    }
  } else { // MODE 2
    float* o = (float*)outp;
    int ncb = gridDim.x;
    float rs[4][4];
#pragma unroll
    for (int i=0;i<4;++i)
#pragma unroll
      for (int j=0;j<4;++j) rs[i][j]=0.f;
#pragma unroll
    for (int mf=0; mf<4; ++mf){
      int r0 = m0 + wm*64 + mf*16 + ((l>>4)<<2);
      int s = r0 >> 5, b0 = r0 & 31;
#pragma unroll
      for (int nf=0; nf<4; ++nf){
        int col = n0 + wn*64 + nf*16 + (l&15);
        if (col < Nreal){
          float bv = bias[col];
#pragma unroll
          for (int j=0;j<4;++j){
            float e = __expf(acc[mf][nf][j] + bv);
            o[(size_t)((b0+j)*128 + s)*Nreal + col] = e;
            rs[mf][j] += e;
          }
        }
      }
    }
#pragma unroll
    for (int mf=0; mf<4; ++mf)
#pragma unroll
      for (int j=0;j<4;++j){
        float v = rs[mf][j];
        v += __shfl_xor(v,1); v += __shfl_xor(v,2); v += __shfl_xor(v,4); v += __shfl_xor(v,8);
        if ((l&15)==0){
          int r = m0 + wm*64 + mf*16 + ((l>>4)<<2) + j;
          int orow = (r&31)*128 + (r>>5);
          psum[(size_t)orow*(2*ncb) + blockIdx.x*2 + wn] = v;
        }
      }
  }
}

// ---------------- encoder scan: 32 worker WGs + fillers, x 512 thr ----------------
__global__ __launch_bounds__(512,1) void enc_scan(
  const short* __restrict__ gxfT, const short* __restrict__ gxbT,
  const short* __restrict__ WhfT, const short* __restrict__ WhbT,
  const float* __restrict__ brf, const float* __restrict__ brb,
  float* __restrict__ hT, u32* __restrict__ hrowB,
  short* __restrict__ encT, u32* __restrict__ flags)
{
  const int tid = threadIdx.x, wg = blockIdx.x;
  if (wg >= 32){ filler_spin(&flags[0]); return; }

  __shared__ __align__(16) short As[32*512];
  __shared__ float accL[96][36];
  __shared__ float brL[96];
  const int dir = wg >> 4, j = wg & 15;
  const short* gxT = dir ? gxbT : gxfT;
  const short* WT  = dir ? WhbT : WhfT;
  const float* br  = dir ? brb  : brf;
  float* hTd  = hT + (size_t)dir*2*16384;
  u32* hrowBd = hrowB + (size_t)dir*2*8192;
  u32* flg    = flags + dir*16*32;
  const int l = tid & 63, wv = tid >> 6;

  if (tid < 96) brL[tid] = br[(tid>>5)*512 + j*32 + (tid&31)];

  bf16x8 bfr[2][16];
  if (wv < 3){
#pragma unroll
    for (int p=0;p<2;++p){
      int gcol = wv*512 + j*32 + p*16 + (l&15);
      const short* bp = WT + (size_t)gcol*512 + ((l>>4)<<3);
#pragma unroll
      for (int kt=0; kt<16; ++kt) bfr[p][kt] = *(const bf16x8*)(bp + kt*32);
    }
  }

  for (int t=0; t<128; ++t){
    const int s = dir ? (127-t) : t;
    const int cur = t & 1, nxt = cur ^ 1;
    if (t > 0){
      if (tid < 16) pollslot(&flg[tid*32], (u32)t);
      __syncthreads();
    }
#pragma unroll
    for (int it=0; it<8; ++it){
      int u = tid + it*512;
      int b = u >> 7, k4 = u & 127;
      u64 v = cohl8(&hrowBd[(cur*32 + b)*256 + k4*2]);
      *(u64*)((char*)As + b*1024 + ((k4*8) ^ ((b&15)<<4))) = v;
    }
    __syncthreads();
    if (wv < 3){
      f32x4 acc[2][2];
#pragma unroll
      for (int m=0;m<2;++m){ acc[m][0]=(f32x4){0,0,0,0}; acc[m][1]=(f32x4){0,0,0,0}; }
#pragma unroll
      for (int kt=0; kt<16; ++kt){
#pragma unroll
        for (int m=0;m<2;++m){
          int row = m*16 + (l&15);
          int kbyte = (kt*4 + (l>>4))*16;
          bf16x8 af = *(const bf16x8*)((char*)As + row*1024 + (kbyte ^ ((row&15)<<4)));
          acc[m][0] = __builtin_amdgcn_mfma_f32_16x16x32_bf16(af, bfr[0][kt], acc[m][0], 0,0,0);
          acc[m][1] = __builtin_amdgcn_mfma_f32_16x16x32_bf16(af, bfr[1][kt], acc[m][1], 0,0,0);
        }
      }
#pragma unroll
      for (int m=0;m<2;++m)
#pragma unroll
        for (int p=0;p<2;++p)
          *(f32x4*)&accL[wv*32 + p*16 + (l&15)][m*16 + ((l>>4)<<2)] = acc[m][p];
    }
    __syncthreads();
    {
      int b = tid & 31, hcp = tid >> 5;
      int hc0 = hcp*2;
      float hn[2];
#pragma unroll
      for (int q=0;q<2;++q){
        int hc = hc0 + q, hcol = j*32 + hc;
        float xz = bf2f(gxT[((size_t)s*1536 + hcol)*32 + b]);
        float xr = bf2f(gxT[((size_t)s*1536 + 512 + hcol)*32 + b]);
        float xh = bf2f(gxT[((size_t)s*1536 + 1024 + hcol)*32 + b]);
        float gz = accL[hc][b]    + brL[hc];
        float gr = accL[32+hc][b] + brL[32+hc];
        float gh = accL[64+hc][b] + brL[64+hc];
        float z = sig_p(xz + gz);
        float r = sig_p(xr + gr);
        float hcand = tanhf(xh + r*gh);
        float hp = hTd[cur*16384 + hcol*32 + b];
        hn[q] = z*hp + (1.f-z)*hcand;
        hTd[nxt*16384 + hcol*32 + b] = hn[q];
        encT[((size_t)s*1024 + dir*512 + hcol)*32 + b] = f2bf(hn[q]);
      }
      u32 pv = ((u32)(unsigned short)f2bf(hn[1])<<16) | (u32)(unsigned short)f2bf(hn[0]);
      cohs4(&hrowBd[(nxt*32 + b)*256 + j*16 + hcp], pv);
    }
    __syncthreads();
    if (tid == 0) cohs4(&flg[j*32], (u32)(t+1));
  }
}

// ---------------- decoder init: fill hrowB buf0 ----------------
__global__ void dec_init(const float* __restrict__ src, u32* __restrict__ hrowB){
  int i = blockIdx.x*256 + threadIdx.x;   // 8192 = 32 b x 256 k2
  int b = i >> 8, k2 = i & 255;
  float v0 = src[(k2*2)*32 + b];
  float v1 = src[(k2*2+1)*32 + b];
  hrowB[b*256 + k2] = ((u32)(unsigned short)f2bf(v1)<<16) | (u32)(unsigned short)f2bf(v0);
}

// ---------------- decoder scan: 48 worker WGs + fillers, x 512 thr ----------------
// wg 0..15 : gh WG j (32 hcols, Whd frags in VGPR): h -> GH[j][96][32]
// wg 16..47: attn+GRU WG, one batch b: full attention + pointwise, owns h[b]
__global__ __launch_bounds__(512,1) void dec_scan(
  const short* __restrict__ gxeR,   // [(t*32+b)][1536] bf16 (incl bi_d)
  const short* __restrict__ encx,   // [b][1536][128] bf16
  const short* __restrict__ WhdT,   // [1536][512] bf16
  const float* __restrict__ brd,
  const short* __restrict__ Wa, const short* __restrict__ Uenc, const float* __restrict__ Va,
  const float* __restrict__ h0,     // [512][32] f32
  u32* __restrict__ hrowB,          // [2][32][256] u32 (bf16 pairs)
  float* __restrict__ GH,           // [16][96][32] f32
  short* __restrict__ decRow,       // [(t*32+b)][512] bf16
  u32* __restrict__ hflag, u32* __restrict__ gflag)
{
  const int tid = threadIdx.x, wg = blockIdx.x;
  if (wg >= 48){ filler_spin(&hflag[0]); return; }

  // gh-WG shared
  __shared__ __align__(16) short As[32*512];
  __shared__ float accL[96][36];
  // attn-WG shared
  __shared__ float hs[512];
  __shared__ float gxc[1536];
  __shared__ float brA[1536];
  __shared__ float whp[128*5];
  __shared__ float whv[128];
  __shared__ float scp[128*5];
  __shared__ float sc[128];
  __shared__ float red[4];
  __shared__ float vL[128];
  __shared__ float aL[128];

  const int l = tid & 63, wv = tid >> 6;

  if (wg < 16){
    // ---- gh WG j ----
    const int j = wg;
    bf16x8 bfr[2][16];
    if (wv < 3){
#pragma unroll
      for (int p=0;p<2;++p){
        int gcol = wv*512 + j*32 + p*16 + (l&15);
        const short* bp = WhdT + (size_t)gcol*512 + ((l>>4)<<3);
#pragma unroll
        for (int kt=0; kt<16; ++kt) bfr[p][kt] = *(const bf16x8*)(bp + kt*32);
      }
    }
    for (int t=0; t<128; ++t){
      const int cur = t & 1;
      if (t > 0){
        if (tid < 32) pollslot(&hflag[tid*32], (u32)t);
        __syncthreads();
      }
      // stage h^{(t)}
#pragma unroll
      for (int it=0; it<8; ++it){
        int u = tid + it*512;
        int b = u >> 7, k4 = u & 127;
        u64 v = cohl8(&hrowB[((size_t)cur*32 + b)*256 + k4*2]);
        *(u64*)((char*)As + b*1024 + ((k4*8) ^ ((b&15)<<4))) = v;
      }
      __syncthreads();
      if (wv < 3){
        f32x4 acc[2][2];
#pragma unroll
        for (int m=0;m<2;++m){ acc[m][0]=(f32x4){0,0,0,0}; acc[m][1]=(f32x4){0,0,0,0}; }
#pragma unroll
        for (int kt=0; kt<16; ++kt){
#pragma unroll
          for (int m=0;m<2;++m){
            int row = m*16 + (l&15);
            int kbyte = (kt*4 + (l>>4))*16;
            bf16x8 af = *(const bf16x8*)((char*)As + row*1024 + (kbyte ^ ((row&15)<<4)));
            acc[m][0] = __builtin_amdgcn_mfma_f32_16x16x32_bf16(af, bfr[0][kt], acc[m][0], 0,0,0);
            acc[m][1] = __builtin_amdgcn_mfma_f32_16x16x32_bf16(af, bfr[1][kt], acc[m][1], 0,0,0);
          }
        }
#pragma unroll
        for (int m=0;m<2;++m)
#pragma unroll
          for (int p=0;p<2;++p)
            *(f32x4*)&accL[wv*32 + p*16 + (l&15)][m*16 + ((l>>4)<<2)] = acc[m][p];
      }
      __syncthreads();
      // publish GH coalesced: GH[j][r][b], r = p*32+c
#pragma unroll
      for (int i=0;i<6;++i){
        int idx = i*512 + tid;
        cohsf(&GH[(size_t)j*3072 + idx], accL[idx>>5][idx&31]);
      }
      __syncthreads();
      if (tid == 0) cohs4(&gflag[j*32], (u32)(t+1));
    }
  } else {
    // ---- attn+GRU WG, batch b ----
    const int b = wg - 16;
    u32 wa[64];
    {
      const u32* wp = (const u32*)(Wa + (size_t)(tid&127)*512 + (tid>>7)*128);
#pragma unroll
      for (int i=0;i<64;++i) wa[i] = wp[i];
    }
    u32 ue[16];
    {
      int s = tid & 127, aq = tid >> 7;
      const u32* up = (const u32*)(Uenc + ((size_t)(s*32 + b))*128 + aq*32);
#pragma unroll
      for (int i=0;i<16;++i) ue[i] = up[i];
    }
    if (tid < 128) vL[tid] = Va[tid];
    for (int i = tid; i < 1536; i += 512) brA[i] = brd[i];
    hs[tid] = h0[(size_t)tid*32 + b];
    const short* eb = encx + (size_t)b*1536*128;
    __syncthreads();

    for (int t=0; t<128; ++t){
      // wh = h @ Wa^T (k split 4-way)  [h local in LDS]
      {
        int a = tid & 127, kq2 = tid >> 7;
        float p = 0.f;
        const float* hp2 = &hs[kq2*128];
#pragma unroll 8
        for (int i=0;i<64;++i){
          u32 w2 = wa[i];
          float2 h2 = *(const float2*)(hp2 + 2*i);
          p += bf2f((short)(w2 & 0xffff))*h2.x + bf2f((short)(w2 >> 16))*h2.y;
        }
        whp[a*5 + kq2] = p;
      }
      __syncthreads();
      if (tid < 128) whv[tid] = whp[tid*5]+whp[tid*5+1]+whp[tid*5+2]+whp[tid*5+3];
      __syncthreads();
      // score_s = sum_a tanh(wh_a + Uenc) * v_a (a split 4-way)
      {
        int s = tid & 127, aq = tid >> 7;
        float p = 0.f;
#pragma unroll 4
        for (int i=0;i<16;++i){
          u32 u2 = ue[i];
          int a0 = aq*32 + 2*i;
          p += tanh_fast(whv[a0]   + bf2f((short)(u2 & 0xffff))) * vL[a0];
          p += tanh_fast(whv[a0+1] + bf2f((short)(u2 >> 16)))    * vL[a0+1];
        }
        scp[s*5 + aq] = p;
      }
      __syncthreads();
      if (tid < 128) sc[tid] = scp[tid*5]+scp[tid*5+1]+scp[tid*5+2]+scp[tid*5+3];
      __syncthreads();
      float ev = 0.f;
      if (tid < 128){
        float v = sc[tid], mx = v;
#pragma unroll
        for (int d2=32; d2; d2>>=1) mx = fmaxf(mx, __shfl_xor(mx, d2));
        if ((tid & 63) == 0) red[tid>>6] = mx;
      }
      __syncthreads();
      if (tid < 128){
        float mx = fmaxf(red[0], red[1]);
        ev = __expf(sc[tid] - mx);
        float sm = ev;
#pragma unroll
        for (int d2=32; d2; d2>>=1) sm += __shfl_xor(sm, d2);
        if ((tid & 63) == 0) red[2 + (tid>>6)] = sm;
      }
      __syncthreads();
      if (tid < 128) aL[tid] = ev / (red[2] + red[3]);
      __syncthreads();
      // gxctx: 3 cols/thread from L2-resident ENCX slice
      {
        int col = tid*3;
        float a0=0.f, a1=0.f, a2=0.f;
        const short* e0 = eb + (size_t)col*128;
#pragma unroll
        for (int sb=0; sb<16; ++sb){
          f32x4 av0 = *(const f32x4*)&aL[sb*8];
          f32x4 av1 = *(const f32x4*)&aL[sb*8+4];
          bf16x8 ev0 = *(const bf16x8*)(e0 + sb*8);
          bf16x8 ev1 = *(const bf16x8*)(e0 + 128 + sb*8);
          bf16x8 ev2 = *(const bf16x8*)(e0 + 256 + sb*8);
#pragma unroll
          for (int i=0;i<4;++i){
            a0 += bf2f(ev0[i])*av0[i]; a1 += bf2f(ev1[i])*av0[i]; a2 += bf2f(ev2[i])*av0[i];
            a0 += bf2f(ev0[4+i])*av1[i]; a1 += bf2f(ev1[4+i])*av1[i]; a2 += bf2f(ev2[4+i])*av1[i];
          }
        }
        gxc[col] = a0; gxc[col+1] = a1; gxc[col+2] = a2;
      }
      __syncthreads();
      // prefetch gx (independent of GH), then wait for GH_t
      const short* gx = gxeR + ((size_t)t*32 + b)*1536;
      float gx0 = bf2f(gx[tid])        + gxc[tid];
      float gx1 = bf2f(gx[512 + tid])  + gxc[512 + tid];
      float gx2 = bf2f(gx[1024 + tid]) + gxc[1024 + tid];
      if (tid < 16) pollslot(&gflag[tid*32], (u32)(t+1));
      __syncthreads();
      // read GH slice + pointwise; col = tid -> j = tid>>5, c = tid&31
      {
        size_t gb = (size_t)(tid>>5)*3072 + (size_t)(tid&31)*32 + b;
        float gh0 = cohlf(&GH[gb]);
        float gh1 = cohlf(&GH[gb + 1024]);
        float gh2 = cohlf(&GH[gb + 2048]);
        float z = sig_p(gx0 + gh0 + brA[tid]);
        float r = sig_p(gx1 + gh1 + brA[512 + tid]);
        float hcand = tanhf(gx2 + r*(gh2 + brA[1024 + tid]));
        float hp = hs[tid];
        float hn = z*hp + (1.f-z)*hcand;
        hs[tid] = hn;
        short mybf = f2bf(hn);
        decRow[((size_t)t*32 + b)*512 + tid] = mybf;
        u32 self16 = (u32)(unsigned short)mybf;
        u32 oth = (u32)__shfl_xor((int)self16, 1);
        if (!(tid & 1))
          cohs4(&hrowB[((size_t)((t+1)&1)*32 + b)*256 + (tid>>1)], self16 | (oth<<16));
      }
      __syncthreads();
      if (tid == 0) cohs4(&hflag[b*32], (u32)(t+1));
    }
  }
}

// ---------------- softmax finish ----------------
__global__ void scale_rows(float* __restrict__ out, const float* __restrict__ psum,
                           int ncols, int w){
  int r = blockIdx.x;
  __shared__ float ssum[256];
  float s = 0.f;
  for (int i = threadIdx.x; i < w; i += 256) s += psum[(size_t)r*w + i];
  ssum[threadIdx.x] = s; __syncthreads();
  for (int d = 128; d; d >>= 1){
    if (threadIdx.x < d) ssum[threadIdx.x] += ssum[threadIdx.x + d];
    __syncthreads();
  }
  float v = 1.f/ssum[0];
  float* p = out + (size_t)r*ncols;
  for (int i = threadIdx.x; i < ncols; i += 256) p[i] *= v;
}

// ---------------- host ----------------
extern "C" void kernel_launch(void* const* d_in, const int* in_sizes, int n_in,
                              void* d_out, int out_size, void* d_ws, size_t ws_size,
                              hipStream_t stream)
{
  const int*   tokens=(const int*)  d_in[0];
  const float* emb  =(const float*)d_in[1];
  const float* Wx_f =(const float*)d_in[2];
  const float* Wh_f =(const float*)d_in[3];
  const float* bi_f =(const float*)d_in[4];
  const float* br_f =(const float*)d_in[5];
  const float* Wx_b =(const float*)d_in[6];
  const float* Wh_b =(const float*)d_in[7];
  const float* bi_b =(const float*)d_in[8];
  const float* br_b =(const float*)d_in[9];
  const float* W_a  =(const float*)d_in[10];
  const float* U_a  =(const float*)d_in[11];
  const float* V_a  =(const float*)d_in[12];
  const float* Wx_d =(const float*)d_in[13];
  const float* Wh_d =(const float*)d_in[14];
  const float* bi_d =(const float*)d_in[15];
  const float* br_d =(const float*)d_in[16];
  const float* Wo   =(const float*)d_in[17];
  const float* bo   =(const float*)d_in[18];

  const int NV = 32001, NVP = 32128, NCB = 251;

  char* base = (char*)d_ws; size_t off = 0;
  auto alloc = [&](size_t bytes)->char*{
    off = (off + 255) & ~(size_t)255;
    char* p = base + off; off += bytes; return p;
  };
  u32*   flags  = (u32*)  alloc(16384);  // enc [0..1023], hflag [1024..2047], gflag [2048..2559]
  short* X      = (short*)alloc((size_t)4096*256*2);
  short* WxfT   = (short*)alloc((size_t)1536*256*2);
  short* WxbT   = (short*)alloc((size_t)1536*256*2);
  short* WhfT   = (short*)alloc((size_t)1536*512*2);
  short* WhbT   = (short*)alloc((size_t)1536*512*2);
  short* WhdT   = (short*)alloc((size_t)1536*512*2);
  short* WxeT   = (short*)alloc((size_t)1536*1024*2);
  short* WxcT   = (short*)alloc((size_t)1536*1024*2);
  short* WoT    = (short*)alloc((size_t)NVP*512*2);
  short* UaB    = (short*)alloc((size_t)128*1024*2);
  short* WaB    = (short*)alloc((size_t)128*512*2);
  short* gxfT   = (short*)alloc((size_t)128*1536*32*2);
  short* gxbT   = (short*)alloc((size_t)128*1536*32*2);
  short* encT   = (short*)alloc((size_t)128*1024*32*2);
  short* encRow = (short*)alloc((size_t)4096*1024*2);
  short* Uenc   = (short*)alloc((size_t)4096*128*2);
  short* gxeR   = (short*)alloc((size_t)4096*1536*2);    // [(t*32+b)][1536]
  short* encxT1 = (short*)alloc((size_t)128*1536*32*2);  // [s][1536][32]
  short* encx   = (short*)alloc((size_t)32*1536*128*2);  // [b][1536][128]
  short* decRow = (short*)alloc((size_t)4096*512*2);
  float* hT_e   = (float*)alloc((size_t)2*2*512*32*4);
  u32*   hrowB_e= (u32*)  alloc((size_t)2*2*32*256*4);
  u32*   hrowB_d= (u32*)  alloc((size_t)2*32*256*4);
  float* GH     = (float*)alloc((size_t)16*96*32*4);
  float* psum   = (float*)alloc((size_t)4096*2*NCB*4);

  hipMemsetAsync(flags, 0, 16384, stream);
  hipMemsetAsync(hT_e, 0, (size_t)2*2*512*32*4, stream);
  hipMemsetAsync(hrowB_e, 0, (size_t)2*2*32*256*4, stream);

  // weight conversions (all BT = [N][K] bf16)
  tconv<<<dim3(1536/32,256/32),dim3(32,8),0,stream>>>(Wx_f, WxfT, 256, 1536, 1536);
  tconv<<<dim3(1536/32,256/32),dim3(32,8),0,stream>>>(Wx_b, WxbT, 256, 1536, 1536);
  tconv<<<dim3(1536/32,512/32),dim3(32,8),0,stream>>>(Wh_f, WhfT, 512, 1536, 1536);
  tconv<<<dim3(1536/32,512/32),dim3(32,8),0,stream>>>(Wh_b, WhbT, 512, 1536, 1536);
  tconv<<<dim3(1536/32,512/32),dim3(32,8),0,stream>>>(Wh_d, WhdT, 512, 1536, 1536);
  tconv<<<dim3(1536/32,1024/32),dim3(32,8),0,stream>>>(Wx_d,                    WxeT, 1024, 1536, 1536);
  tconv<<<dim3(1536/32,1024/32),dim3(32,8),0,stream>>>(Wx_d+(size_t)1024*1536,  WxcT, 1024, 1536, 1536);
  tconv<<<dim3(NVP/32,512/32),dim3(32,8),0,stream>>>(Wo, WoT, 512, NV, NVP);
  cvt1d<<<(128*512+255)/256,256,0,stream>>>(W_a, WaB, 128*512);
  cvt1d<<<(128*1024+255)/256,256,0,stream>>>(U_a, UaB, 128*1024);

  embed_k<<<4096,256,0,stream>>>(tokens, emb, X);

  gemm_k<1><<<dim3(12,32),256,0,stream>>>(X, WxfT, bi_f, gxfT, nullptr, 1536, 256, 1536);
  gemm_k<1><<<dim3(12,32),256,0,stream>>>(X, WxbT, bi_b, gxbT, nullptr, 1536, 256, 1536);

  enc_scan<<<256,512,0,stream>>>(gxfT, gxbT, WhfT, WhbT, br_f, br_b,
                                 hT_e, hrowB_e, encT, flags);

  btrans<<<dim3(1024/32,128),dim3(32,8),0,stream>>>(encT, encRow, 1024);

  gemm_k<3><<<dim3(1,32),256,0,stream>>>(encRow, UaB, nullptr, Uenc, nullptr, 128, 1024, 128);
  gemm_k<3><<<dim3(12,32),256,0,stream>>>(encRow, WxeT, bi_d, gxeR, nullptr, 1536, 1024, 1536);
  gemm_k<1><<<dim3(12,32),256,0,stream>>>(encRow, WxcT, nullptr, encxT1, nullptr, 1536, 1024, 1536);
  etrans<<<1536,256,0,stream>>>(encxT1, encx);

  // decoder h0 = backward final h (dir=1, buf0)
  dec_init<<<32,256,0,stream>>>(hT_e + 32768, hrowB_d);

  dec_scan<<<256,512,0,stream>>>(gxeR, encx, WhdT, br_d, WaB, Uenc, V_a,
                                 hT_e + 32768, hrowB_d, GH, decRow,
                                 &flags[1024], &flags[2048]);

  gemm_k<2><<<dim3(NCB,32),256,0,stream>>>(decRow, WoT, bo, d_out, psum, NV, 512, NV);

  scale_rows<<<4096,256,0,stream>>>((float*)d_out, psum, NV, 2*NCB);
}

// Round 6
// 3783.471 us; speedup vs baseline: 1.1057x; 1.1057x over previous
//
#include <hip/hip_runtime.h>
#include <stdint.h>

typedef unsigned int u32;
typedef unsigned long long u64;
typedef __attribute__((ext_vector_type(8))) short bf16x8;
typedef __attribute__((ext_vector_type(4))) float f32x4;
typedef __attribute__((ext_vector_type(4))) int i32x4;
typedef __attribute__((ext_vector_type(2))) int i32x2;

#define DEV static __device__ __forceinline__

DEV short f2bf(float f){ u32 u=__float_as_uint(f); return (short)((u + 0x7fffu + ((u>>16)&1u))>>16); }
DEV float bf2f(short s){ return __uint_as_float(((u32)(unsigned short)s)<<16); }
DEV float sig_p(float x){ return 1.f/(1.f+expf(-x)); }
DEV float tanh_fast(float x){ float e=__expf(2.f*x); return 1.f-2.f/(e+1.f); }

// coherent (LLC, cache-bypass) ops: used ONLY for publishes and flag polls
DEV u32  cohl4(const u32* p){ return __hip_atomic_load(p, __ATOMIC_RELAXED, __HIP_MEMORY_SCOPE_AGENT); }
DEV void cohs4(u32* p, u32 v){ __hip_atomic_store(p, v, __ATOMIC_RELAXED, __HIP_MEMORY_SCOPE_AGENT); }
DEV void cohs8(void* p, u64 v){ __hip_atomic_store((u64*)p, v, __ATOMIC_RELAXED, __HIP_MEMORY_SCOPE_AGENT); }
DEV void pollnz(const u32* s){ while (cohl4(s) == 0u) {} }

// ---------------- convert / transpose kernels ----------------

__global__ void cvt1d(const float* __restrict__ in, short* __restrict__ out, int n){
  int i = blockIdx.x*256 + threadIdx.x;
  if (i < n) out[i] = f2bf(in[i]);
}

// in f32 [R][C] -> out bf16 [Cpad][R]
__global__ void tconv(const float* __restrict__ in, short* __restrict__ out, int R, int C, int Cpad){
  __shared__ float t[32][33];
  int tx = threadIdx.x, ty = threadIdx.y;
  int c0 = blockIdx.x*32, r0 = blockIdx.y*32;
#pragma unroll
  for (int j=0;j<4;++j){
    int r = r0 + ty + 8*j, c = c0 + tx;
    t[ty+8*j][tx] = (c < C) ? in[(size_t)r*C + c] : 0.f;
  }
  __syncthreads();
#pragma unroll
  for (int j=0;j<4;++j){
    int oc = c0 + ty + 8*j;
    out[(size_t)oc*R + r0 + tx] = f2bf(t[tx][ty+8*j]);
  }
}

// batched transpose: in bf16 [NB][Dd][32] -> out bf16 [NB*32][Dd]
__global__ void btrans(const short* __restrict__ in, short* __restrict__ out, int Dd){
  __shared__ short t[32][33];
  int tx = threadIdx.x, ty = threadIdx.y;
  int d0 = blockIdx.x*32, s = blockIdx.y;
#pragma unroll
  for (int j=0;j<4;++j)
    t[ty+8*j][tx] = in[((size_t)s*Dd + d0 + ty + 8*j)*32 + tx];
  __syncthreads();
#pragma unroll
  for (int j=0;j<4;++j)
    out[((size_t)(s*32 + ty + 8*j))*Dd + d0 + tx] = t[tx][ty+8*j];
}

// [s][1536][32] -> [b][1536][128]
__global__ void etrans(const short* __restrict__ in, short* __restrict__ out){
  __shared__ short t[128][33];
  int c = blockIdx.x, tid = threadIdx.x;
#pragma unroll
  for (int i=0;i<16;++i){
    int idx = tid + i*256;
    t[idx>>5][idx&31] = in[((size_t)(idx>>5)*1536 + c)*32 + (idx&31)];
  }
  __syncthreads();
#pragma unroll
  for (int i=0;i<16;++i){
    int idx = tid + i*256;
    out[((size_t)(idx>>7)*1536 + c)*128 + (idx&127)] = t[idx&127][idx>>7];
  }
}

__global__ void embed_k(const int* __restrict__ tok, const float* __restrict__ emb, short* __restrict__ X){
  int row = blockIdx.x;               // (s,b)
  int s = row >> 5, b = row & 31;
  int tv = tok[b*128 + s];
  X[(size_t)row*256 + threadIdx.x] = f2bf(emb[(size_t)tv*256 + threadIdx.x]);
}

// ---------------- MFMA GEMM  C = A[M,K] * BT[Npad][K] ----------------
template<int MODE>
__global__ __launch_bounds__(256) void gemm_k(
  const short* __restrict__ A, const short* __restrict__ BT,
  const float* __restrict__ bias, void* __restrict__ outp,
  float* __restrict__ psum, int Nreal, int K, int Ntot)
{
  const int m0 = blockIdx.y * 128, n0 = blockIdx.x * 128;
  const int tid = threadIdx.x, l = tid & 63, wv = tid >> 6;
  const int wm = wv >> 1, wn = wv & 1;
  __shared__ __align__(16) short As[128*64];
  __shared__ __align__(16) short Bs[128*64];
  f32x4 acc[4][4];
#pragma unroll
  for (int i=0;i<4;++i)
#pragma unroll
    for (int j=0;j<4;++j) acc[i][j] = (f32x4){0.f,0.f,0.f,0.f};

  const int nkb = K >> 6;
  for (int kb=0; kb<nkb; ++kb){
#pragma unroll
    for (int i=0;i<4;++i){
      int si = tid + i*256;
      int row = si >> 3, seg = si & 7;
      u32 off = (u32)(row*128 + seg*16) ^ (u32)((row&7)<<4);
      *(i32x4*)((char*)As + off) = *(const i32x4*)(A + (size_t)(m0+row)*K + kb*64 + seg*8);
      *(i32x4*)((char*)Bs + off) = *(const i32x4*)(BT + (size_t)(n0+row)*K + kb*64 + seg*8);
    }
    __syncthreads();
#pragma unroll
    for (int kt=0; kt<2; ++kt){
      bf16x8 af[4], bfv[4];
      int seg = kt*4 + (l>>4);
#pragma unroll
      for (int f=0; f<4; ++f){
        int ra = wm*64 + f*16 + (l&15);
        af[f]  = *(const bf16x8*)((char*)As + (((u32)(ra*128 + seg*16)) ^ ((u32)(ra&7)<<4)));
        int rb = wn*64 + f*16 + (l&15);
        bfv[f] = *(const bf16x8*)((char*)Bs + (((u32)(rb*128 + seg*16)) ^ ((u32)(rb&7)<<4)));
      }
#pragma unroll
      for (int mf=0; mf<4; ++mf)
#pragma unroll
        for (int nf=0; nf<4; ++nf)
          acc[mf][nf] = __builtin_amdgcn_mfma_f32_16x16x32_bf16(af[mf], bfv[nf], acc[mf][nf], 0,0,0);
    }
    __syncthreads();
  }

  if (MODE == 1){
    short* oT = (short*)outp;
#pragma unroll
    for (int mf=0; mf<4; ++mf){
      int r0 = m0 + wm*64 + mf*16 + ((l>>4)<<2);
      int s = r0 >> 5, b0 = r0 & 31;
#pragma unroll
      for (int nf=0; nf<4; ++nf){
        int col = n0 + wn*64 + nf*16 + (l&15);
        float bv = bias ? bias[col] : 0.f;
        short tmp[4];
#pragma unroll
        for (int j=0;j<4;++j) tmp[j] = f2bf(acc[mf][nf][j] + bv);
        *(i32x2*)(oT + ((size_t)s*Ntot + col)*32 + b0) = *(i32x2*)tmp;
      }
    }
  } else if (MODE == 3){
    short* o = (short*)outp;
#pragma unroll
    for (int mf=0; mf<4; ++mf){
      int r0 = m0 + wm*64 + mf*16 + ((l>>4)<<2);
#pragma unroll
      for (int nf=0; nf<4; ++nf){
        int col = n0 + wn*64 + nf*16 + (l&15);
        if (col < Nreal){
          float bv = bias ? bias[col] : 0.f;
#pragma unroll
          for (int j=0;j<4;++j) o[(size_t)(r0+j)*Nreal + col] = f2bf(acc[mf][nf][j] + bv);
        }
      }
    }
  } else { // MODE 2
    float* o = (float*)outp;
    int ncb = gridDim.x;
    float rs[4][4];
#pragma unroll
    for (int i=0;i<4;++i)
#pragma unroll
      for (int j=0;j<4;++j) rs[i][j]=0.f;
#pragma unroll
    for (int mf=0; mf<4; ++mf){
      int r0 = m0 + wm*64 + mf*16 + ((l>>4)<<2);
      int s = r0 >> 5, b0 = r0 & 31;
#pragma unroll
      for (int nf=0; nf<4; ++nf){
        int col = n0 + wn*64 + nf*16 + (l&15);
        if (col < Nreal){
          float bv = bias[col];
#pragma unroll
          for (int j=0;j<4;++j){
            float e = __expf(acc[mf][nf][j] + bv);
            o[(size_t)((b0+j)*128 + s)*Nreal + col] = e;
            rs[mf][j] += e;
          }
        }
      }
    }
#pragma unroll
    for (int mf=0; mf<4; ++mf)
#pragma unroll
      for (int j=0;j<4;++j){
        float v = rs[mf][j];
        v += __shfl_xor(v,1); v += __shfl_xor(v,2); v += __shfl_xor(v,4); v += __shfl_xor(v,8);
        if ((l&15)==0){
          int r = m0 + wm*64 + mf*16 + ((l>>4)<<2) + j;
          int orow = (r&31)*128 + (r>>5);
          psum[(size_t)orow*(2*ncb) + blockIdx.x*2 + wn] = v;
        }
      }
  }
}

// ---------------- encoder scan: 32 WGs (16/dir) x 512 thr, rotated buffers ----------------
// hband: [2 dir][129 t][32 b][256 u32] (bf16 pairs); eflag: [2][129][16][32]u32
__global__ __launch_bounds__(512,1) void enc_scan(
  const short* __restrict__ gxfT, const short* __restrict__ gxbT,
  const short* __restrict__ WhfT, const short* __restrict__ WhbT,
  const float* __restrict__ brf, const float* __restrict__ brb,
  u32* __restrict__ hband, float* __restrict__ hfin,
  short* __restrict__ encT, u32* __restrict__ eflag)
{
  __shared__ __align__(16) short As[32*512];
  __shared__ float accL[96][36];
  __shared__ float brL[96];
  const int tid = threadIdx.x, wg = blockIdx.x;
  const int dir = wg >> 4, j = wg & 15;
  const short* gxT = dir ? gxbT : gxfT;
  const short* WT  = dir ? WhbT : WhfT;
  const float* br  = dir ? brb  : brf;
  u32* hb = hband + (size_t)dir*129*8192;
  u32* fl = eflag + (size_t)dir*129*512;
  const int l = tid & 63, wv = tid >> 6;

  if (tid < 96) brL[tid] = br[(tid>>5)*512 + j*32 + (tid&31)];

  bf16x8 bfr[2][16];
  if (wv < 3){
#pragma unroll
    for (int p=0;p<2;++p){
      int gcol = wv*512 + j*32 + p*16 + (l&15);
      const short* bp = WT + (size_t)gcol*512 + ((l>>4)<<3);
#pragma unroll
      for (int kt=0; kt<16; ++kt) bfr[p][kt] = *(const bf16x8*)(bp + kt*32);
    }
  }

  // persistent f32 h for this thread's 2 hcols (b = tid&31, hcols j*32 + 2*(tid>>5)+{0,1})
  const int pb = tid & 31, php = tid >> 5;
  float hreg[2] = {0.f, 0.f};

  for (int t=0; t<128; ++t){
    const int s = dir ? (127-t) : t;
    if (t > 0){
      if (tid < 16) pollnz(&fl[(size_t)t*512 + tid*32]);
      __syncthreads();
    }
    // stage h_t: plain coalesced 16B loads (fresh rotated address -> coherent)
#pragma unroll
    for (int it=0; it<4; ++it){
      int u = tid + it*512;
      int b = u >> 6, k8 = u & 63;
      i32x4 v = *(const i32x4*)&hb[(size_t)t*8192 + b*256 + k8*4];
      *(i32x4*)((char*)As + b*1024 + ((k8*16) ^ ((b&15)<<4))) = v;
    }
    __syncthreads();
    if (wv < 3){
      f32x4 acc[2][2];
#pragma unroll
      for (int m=0;m<2;++m){ acc[m][0]=(f32x4){0,0,0,0}; acc[m][1]=(f32x4){0,0,0,0}; }
#pragma unroll
      for (int kt=0; kt<16; ++kt){
#pragma unroll
        for (int m=0;m<2;++m){
          int row = m*16 + (l&15);
          int kbyte = (kt*4 + (l>>4))*16;
          bf16x8 af = *(const bf16x8*)((char*)As + row*1024 + (kbyte ^ ((row&15)<<4)));
          acc[m][0] = __builtin_amdgcn_mfma_f32_16x16x32_bf16(af, bfr[0][kt], acc[m][0], 0,0,0);
          acc[m][1] = __builtin_amdgcn_mfma_f32_16x16x32_bf16(af, bfr[1][kt], acc[m][1], 0,0,0);
        }
      }
#pragma unroll
      for (int m=0;m<2;++m)
#pragma unroll
        for (int p=0;p<2;++p)
          *(f32x4*)&accL[wv*32 + p*16 + (l&15)][m*16 + ((l>>4)<<2)] = acc[m][p];
    }
    __syncthreads();
    // pointwise (hp from registers)
    short obf[2];
    {
      int b = pb, hc0 = php*2;
#pragma unroll
      for (int q=0;q<2;++q){
        int hc = hc0 + q, hcol = j*32 + hc;
        float xz = bf2f(gxT[((size_t)s*1536 + hcol)*32 + b]);
        float xr = bf2f(gxT[((size_t)s*1536 + 512 + hcol)*32 + b]);
        float xh = bf2f(gxT[((size_t)s*1536 + 1024 + hcol)*32 + b]);
        float gz = accL[hc][b]    + brL[hc];
        float gr = accL[32+hc][b] + brL[32+hc];
        float gh = accL[64+hc][b] + brL[64+hc];
        float z = sig_p(xz + gz);
        float r = sig_p(xr + gr);
        float hcand = tanhf(xh + r*gh);
        float hn = z*hreg[q] + (1.f-z)*hcand;
        hreg[q] = hn;
        obf[q] = f2bf(hn);
      }
      u32 pv = ((u32)(unsigned short)obf[1]<<16) | (u32)(unsigned short)obf[0];
      cohs4(&hb[(size_t)(t+1)*8192 + b*256 + j*16 + php], pv);
    }
    __syncthreads();                       // drain publishes
    if (tid == 0) cohs4(&fl[(size_t)(t+1)*512 + j*32], 1u);
    // off-critical-path stores
    {
      int b = pb, hc0 = php*2;
      encT[((size_t)s*1024 + dir*512 + (j*32+hc0))*32 + b]   = obf[0];
      encT[((size_t)s*1024 + dir*512 + (j*32+hc0+1))*32 + b] = obf[1];
      if (dir && t == 127){
        hfin[(j*32+hc0)*32 + b]   = hreg[0];
        hfin[(j*32+hc0+1)*32 + b] = hreg[1];
      }
    }
  }
}

// ---------------- decoder init: hband_d[0] from hfin ----------------
__global__ void dec_init(const float* __restrict__ hfin, u32* __restrict__ hband0){
  int i = blockIdx.x*256 + threadIdx.x;   // 8192 = 32 b x 256 k2
  int b = i >> 8, k2 = i & 255;
  float v0 = hfin[(k2*2)*32 + b];
  float v1 = hfin[(k2*2+1)*32 + b];
  hband0[b*256 + k2] = ((u32)(unsigned short)f2bf(v1)<<16) | (u32)(unsigned short)f2bf(v0);
}

// ---------------- decoder scan: 48 WGs x 512 thr, rotated buffers ----------------
// wg 0..15 : gh WG j: stage h_t -> MFMA -> GHband[t][b][1536]
// wg 16..47: attn+GRU WG b: attention + pointwise, owns h[b] in LDS
// hband: [129][32][256]u32; GHband: [128][32][1536]f32
// hflag: [129][32][32]u32; gflag: [128][16][32]u32
__global__ __launch_bounds__(512,1) void dec_scan(
  const short* __restrict__ gxeR,   // [(t*32+b)][1536] bf16 (incl bi_d)
  const short* __restrict__ encx,   // [b][1536][128] bf16
  const short* __restrict__ WhdT,   // [1536][512] bf16
  const float* __restrict__ brd,
  const short* __restrict__ Wa, const short* __restrict__ Uenc, const float* __restrict__ Va,
  const float* __restrict__ hfin,   // [512][32] f32
  u32* __restrict__ hband,
  float* __restrict__ GHband,
  short* __restrict__ decRow,       // [(t*32+b)][512] bf16
  u32* __restrict__ hflag, u32* __restrict__ gflag)
{
  // gh-WG shared
  __shared__ __align__(16) short As[32*512];
  __shared__ float accL[96][36];
  // attn-WG shared
  __shared__ float hs[512];
  __shared__ float gxc[1536];
  __shared__ float brA[1536];
  __shared__ float whp[128*5];
  __shared__ float whv[128];
  __shared__ float scp[128*5];
  __shared__ float sc[128];
  __shared__ float red[4];
  __shared__ float vL[128];
  __shared__ float aL[128];

  const int tid = threadIdx.x, wg = blockIdx.x;
  const int l = tid & 63, wv = tid >> 6;

  if (wg < 16){
    // ---- gh WG j ----
    const int j = wg;
    bf16x8 bfr[2][16];
    if (wv < 3){
#pragma unroll
      for (int p=0;p<2;++p){
        int gcol = wv*512 + j*32 + p*16 + (l&15);
        const short* bp = WhdT + (size_t)gcol*512 + ((l>>4)<<3);
#pragma unroll
        for (int kt=0; kt<16; ++kt) bfr[p][kt] = *(const bf16x8*)(bp + kt*32);
      }
    }
    const int b2 = tid >> 4, q = tid & 15;   // publish mapping
    for (int t=0; t<128; ++t){
      if (t > 0){
        if (tid < 32) pollnz(&hflag[(size_t)t*1024 + tid*32]);
        __syncthreads();
      }
      // stage h_t (plain coalesced 16B loads)
#pragma unroll
      for (int it=0; it<4; ++it){
        int u = tid + it*512;
        int b = u >> 6, k8 = u & 63;
        i32x4 v = *(const i32x4*)&hband[(size_t)t*8192 + b*256 + k8*4];
        *(i32x4*)((char*)As + b*1024 + ((k8*16) ^ ((b&15)<<4))) = v;
      }
      __syncthreads();
      if (wv < 3){
        f32x4 acc[2][2];
#pragma unroll
        for (int m=0;m<2;++m){ acc[m][0]=(f32x4){0,0,0,0}; acc[m][1]=(f32x4){0,0,0,0}; }
#pragma unroll
        for (int kt=0; kt<16; ++kt){
#pragma unroll
          for (int m=0;m<2;++m){
            int row = m*16 + (l&15);
            int kbyte = (kt*4 + (l>>4))*16;
            bf16x8 af = *(const bf16x8*)((char*)As + row*1024 + (kbyte ^ ((row&15)<<4)));
            acc[m][0] = __builtin_amdgcn_mfma_f32_16x16x32_bf16(af, bfr[0][kt], acc[m][0], 0,0,0);
            acc[m][1] = __builtin_amdgcn_mfma_f32_16x16x32_bf16(af, bfr[1][kt], acc[m][1], 0,0,0);
          }
        }
#pragma unroll
        for (int m=0;m<2;++m)
#pragma unroll
          for (int p=0;p<2;++p)
            *(f32x4*)&accL[wv*32 + p*16 + (l&15)][m*16 + ((l>>4)<<2)] = acc[m][p];
      }
      __syncthreads();
      // publish GH: [t][b2][gcol], gcol = (cp>>5)*512 + j*32 + (cp&31); pairs -> 8B stores
      {
        float* gbase = GHband + ((size_t)t*32 + b2)*1536;
#pragma unroll
        for (int pp=0; pp<3; ++pp){
          int cp = q*6 + pp*2;
          float f0 = accL[cp][b2], f1 = accL[cp+1][b2];
          u64 pv = ((u64)__float_as_uint(f1)<<32) | (u64)__float_as_uint(f0);
          cohs8(&gbase[(cp>>5)*512 + j*32 + (cp&31)], pv);
        }
      }
      __syncthreads();
      if (tid == 0) cohs4(&gflag[(size_t)t*512 + j*32], 1u);
    }
  } else {
    // ---- attn+GRU WG, batch b ----
    const int b = wg - 16;
    u32 wa[64];
    {
      const u32* wp = (const u32*)(Wa + (size_t)(tid&127)*512 + (tid>>7)*128);
#pragma unroll
      for (int i=0;i<64;++i) wa[i] = wp[i];
    }
    u32 ue[16];
    {
      int s = tid & 127, aq = tid >> 7;
      const u32* up = (const u32*)(Uenc + ((size_t)(s*32 + b))*128 + aq*32);
#pragma unroll
      for (int i=0;i<16;++i) ue[i] = up[i];
    }
    if (tid < 128) vL[tid] = Va[tid];
    for (int i = tid; i < 1536; i += 512) brA[i] = brd[i];
    hs[tid] = hfin[(size_t)tid*32 + b];
    const short* eb = encx + (size_t)b*1536*128;
    __syncthreads();

    for (int t=0; t<128; ++t){
      // wh = h @ Wa^T (k split 4-way)  [h local in LDS]
      {
        int a = tid & 127, kq2 = tid >> 7;
        float p = 0.f;
        const float* hp2 = &hs[kq2*128];
#pragma unroll 8
        for (int i=0;i<64;++i){
          u32 w2 = wa[i];
          float2 h2 = *(const float2*)(hp2 + 2*i);
          p += bf2f((short)(w2 & 0xffff))*h2.x + bf2f((short)(w2 >> 16))*h2.y;
        }
        whp[a*5 + kq2] = p;
      }
      __syncthreads();
      if (tid < 128) whv[tid] = whp[tid*5]+whp[tid*5+1]+whp[tid*5+2]+whp[tid*5+3];
      __syncthreads();
      // score_s = sum_a tanh(wh_a + Uenc) * v_a (a split 4-way)
      {
        int s = tid & 127, aq = tid >> 7;
        float p = 0.f;
#pragma unroll 4
        for (int i=0;i<16;++i){
          u32 u2 = ue[i];
          int a0 = aq*32 + 2*i;
          p += tanh_fast(whv[a0]   + bf2f((short)(u2 & 0xffff))) * vL[a0];
          p += tanh_fast(whv[a0+1] + bf2f((short)(u2 >> 16)))    * vL[a0+1];
        }
        scp[s*5 + aq] = p;
      }
      __syncthreads();
      if (tid < 128) sc[tid] = scp[tid*5]+scp[tid*5+1]+scp[tid*5+2]+scp[tid*5+3];
      __syncthreads();
      float ev = 0.f;
      if (tid < 128){
        float v = sc[tid], mx = v;
#pragma unroll
        for (int d2=32; d2; d2>>=1) mx = fmaxf(mx, __shfl_xor(mx, d2));
        if ((tid & 63) == 0) red[tid>>6] = mx;
      }
      __syncthreads();
      if (tid < 128){
        float mx = fmaxf(red[0], red[1]);
        ev = __expf(sc[tid] - mx);
        float sm = ev;
#pragma unroll
        for (int d2=32; d2; d2>>=1) sm += __shfl_xor(sm, d2);
        if ((tid & 63) == 0) red[2 + (tid>>6)] = sm;
      }
      __syncthreads();
      if (tid < 128) aL[tid] = ev / (red[2] + red[3]);
      __syncthreads();
      // gxctx: 3 cols/thread from L2-resident ENCX slice
      {
        int col = tid*3;
        float a0=0.f, a1=0.f, a2=0.f;
        const short* e0 = eb + (size_t)col*128;
#pragma unroll
        for (int sb=0; sb<16; ++sb){
          f32x4 av0 = *(const f32x4*)&aL[sb*8];
          f32x4 av1 = *(const f32x4*)&aL[sb*8+4];
          bf16x8 ev0 = *(const bf16x8*)(e0 + sb*8);
          bf16x8 ev1 = *(const bf16x8*)(e0 + 128 + sb*8);
          bf16x8 ev2 = *(const bf16x8*)(e0 + 256 + sb*8);
#pragma unroll
          for (int i=0;i<4;++i){
            a0 += bf2f(ev0[i])*av0[i]; a1 += bf2f(ev1[i])*av0[i]; a2 += bf2f(ev2[i])*av0[i];
            a0 += bf2f(ev0[4+i])*av1[i]; a1 += bf2f(ev1[4+i])*av1[i]; a2 += bf2f(ev2[4+i])*av1[i];
          }
        }
        gxc[col] = a0; gxc[col+1] = a1; gxc[col+2] = a2;
      }
      __syncthreads();
      // prefetch gx, then wait for GH_t and read it (plain coalesced loads)
      const short* gx = gxeR + ((size_t)t*32 + b)*1536;
      float gx0 = bf2f(gx[tid])        + gxc[tid];
      float gx1 = bf2f(gx[512 + tid])  + gxc[512 + tid];
      float gx2 = bf2f(gx[1024 + tid]) + gxc[1024 + tid];
      if (tid < 16) pollnz(&gflag[(size_t)t*512 + tid*32]);
      __syncthreads();
      short mybf;
      {
        const float* ghp = GHband + ((size_t)t*32 + b)*1536;
        float gh0 = ghp[tid];
        float gh1 = ghp[512 + tid];
        float gh2 = ghp[1024 + tid];
        float z = sig_p(gx0 + gh0 + brA[tid]);
        float r = sig_p(gx1 + gh1 + brA[512 + tid]);
        float hcand = tanhf(gx2 + r*(gh2 + brA[1024 + tid]));
        float hp = hs[tid];
        float hn = z*hp + (1.f-z)*hcand;
        hs[tid] = hn;
        mybf = f2bf(hn);
        u32 self16 = (u32)(unsigned short)mybf;
        u32 oth = (u32)__shfl_xor((int)self16, 1);
        if (!(tid & 1))
          cohs4(&hband[(size_t)(t+1)*8192 + b*256 + (tid>>1)], self16 | (oth<<16));
      }
      __syncthreads();                     // drain h publishes (and orders hs for next wh)
      if (tid == 0) cohs4(&hflag[(size_t)(t+1)*1024 + b*32], 1u);
      decRow[((size_t)t*32 + b)*512 + tid] = mybf;   // off critical path
    }
  }
}

// ---------------- softmax finish ----------------
__global__ void scale_rows(float* __restrict__ out, const float* __restrict__ psum,
                           int ncols, int w){
  int r = blockIdx.x;
  __shared__ float ssum[256];
  float s = 0.f;
  for (int i = threadIdx.x; i < w; i += 256) s += psum[(size_t)r*w + i];
  ssum[threadIdx.x] = s; __syncthreads();
  for (int d = 128; d; d >>= 1){
    if (threadIdx.x < d) ssum[threadIdx.x] += ssum[threadIdx.x + d];
    __syncthreads();
  }
  float v = 1.f/ssum[0];
  float* p = out + (size_t)r*ncols;
  for (int i = threadIdx.x; i < ncols; i += 256) p[i] *= v;
}

// ---------------- host ----------------
extern "C" void kernel_launch(void* const* d_in, const int* in_sizes, int n_in,
                              void* d_out, int out_size, void* d_ws, size_t ws_size,
                              hipStream_t stream)
{
  const int*   tokens=(const int*)  d_in[0];
  const float* emb  =(const float*)d_in[1];
  const float* Wx_f =(const float*)d_in[2];
  const float* Wh_f =(const float*)d_in[3];
  const float* bi_f =(const float*)d_in[4];
  const float* br_f =(const float*)d_in[5];
  const float* Wx_b =(const float*)d_in[6];
  const float* Wh_b =(const float*)d_in[7];
  const float* bi_b =(const float*)d_in[8];
  const float* br_b =(const float*)d_in[9];
  const float* W_a  =(const float*)d_in[10];
  const float* U_a  =(const float*)d_in[11];
  const float* V_a  =(const float*)d_in[12];
  const float* Wx_d =(const float*)d_in[13];
  const float* Wh_d =(const float*)d_in[14];
  const float* bi_d =(const float*)d_in[15];
  const float* br_d =(const float*)d_in[16];
  const float* Wo   =(const float*)d_in[17];
  const float* bo   =(const float*)d_in[18];

  const int NV = 32001, NVP = 32128, NCB = 251;

  char* base = (char*)d_ws; size_t off = 0;
  auto alloc = [&](size_t bytes)->char*{
    off = (off + 255) & ~(size_t)255;
    char* p = base + off; off += bytes; return p;
  };
  u32*   eflag  = (u32*)  alloc((size_t)2*129*512*4);      // [2][129][16][32]
  u32*   hflag  = (u32*)  alloc((size_t)129*1024*4);       // [129][32][32]
  u32*   gflag  = (u32*)  alloc((size_t)128*512*4);        // [128][16][32]
  u32*   hband_e= (u32*)  alloc((size_t)2*129*8192*4);     // [2][129][32][256]
  u32*   hband_d= (u32*)  alloc((size_t)129*8192*4);       // [129][32][256]
  float* GHband = (float*)alloc((size_t)128*32*1536*4);    // [128][32][1536]
  float* hfin   = (float*)alloc((size_t)512*32*4);
  short* X      = (short*)alloc((size_t)4096*256*2);
  short* WxfT   = (short*)alloc((size_t)1536*256*2);
  short* WxbT   = (short*)alloc((size_t)1536*256*2);
  short* WhfT   = (short*)alloc((size_t)1536*512*2);
  short* WhbT   = (short*)alloc((size_t)1536*512*2);
  short* WhdT   = (short*)alloc((size_t)1536*512*2);
  short* WxeT   = (short*)alloc((size_t)1536*1024*2);
  short* WxcT   = (short*)alloc((size_t)1536*1024*2);
  short* WoT    = (short*)alloc((size_t)NVP*512*2);
  short* UaB    = (short*)alloc((size_t)128*1024*2);
  short* WaB    = (short*)alloc((size_t)128*512*2);
  short* gxfT   = (short*)alloc((size_t)128*1536*32*2);
  short* gxbT   = (short*)alloc((size_t)128*1536*32*2);
  short* encT   = (short*)alloc((size_t)128*1024*32*2);
  short* encRow = (short*)alloc((size_t)4096*1024*2);
  short* Uenc   = (short*)alloc((size_t)4096*128*2);
  short* gxeR   = (short*)alloc((size_t)4096*1536*2);
  short* encxT1 = (short*)alloc((size_t)128*1536*32*2);
  short* encx   = (short*)alloc((size_t)32*1536*128*2);
  short* decRow = (short*)alloc((size_t)4096*512*2);
  float* psum   = (float*)alloc((size_t)4096*2*NCB*4);

  hipMemsetAsync(eflag, 0, (size_t)2*129*512*4, stream);
  hipMemsetAsync(hflag, 0, (size_t)129*1024*4, stream);
  hipMemsetAsync(gflag, 0, (size_t)128*512*4, stream);
  hipMemsetAsync(hband_e, 0, (size_t)2*129*8192*4, stream);   // only t=0 strictly needed

  // weight conversions (all BT = [N][K] bf16)
  tconv<<<dim3(1536/32,256/32),dim3(32,8),0,stream>>>(Wx_f, WxfT, 256, 1536, 1536);
  tconv<<<dim3(1536/32,256/32),dim3(32,8),0,stream>>>(Wx_b, WxbT, 256, 1536, 1536);
  tconv<<<dim3(1536/32,512/32),dim3(32,8),0,stream>>>(Wh_f, WhfT, 512, 1536, 1536);
  tconv<<<dim3(1536/32,512/32),dim3(32,8),0,stream>>>(Wh_b, WhbT, 512, 1536, 1536);
  tconv<<<dim3(1536/32,512/32),dim3(32,8),0,stream>>>(Wh_d, WhdT, 512, 1536, 1536);
  tconv<<<dim3(1536/32,1024/32),dim3(32,8),0,stream>>>(Wx_d,                    WxeT, 1024, 1536, 1536);
  tconv<<<dim3(1536/32,1024/32),dim3(32,8),0,stream>>>(Wx_d+(size_t)1024*1536,  WxcT, 1024, 1536, 1536);
  tconv<<<dim3(NVP/32,512/32),dim3(32,8),0,stream>>>(Wo, WoT, 512, NV, NVP);
  cvt1d<<<(128*512+255)/256,256,0,stream>>>(W_a, WaB, 128*512);
  cvt1d<<<(128*1024+255)/256,256,0,stream>>>(U_a, UaB, 128*1024);

  embed_k<<<4096,256,0,stream>>>(tokens, emb, X);

  gemm_k<1><<<dim3(12,32),256,0,stream>>>(X, WxfT, bi_f, gxfT, nullptr, 1536, 256, 1536);
  gemm_k<1><<<dim3(12,32),256,0,stream>>>(X, WxbT, bi_b, gxbT, nullptr, 1536, 256, 1536);

  enc_scan<<<32,512,0,stream>>>(gxfT, gxbT, WhfT, WhbT, br_f, br_b,
                                hband_e, hfin, encT, eflag);

  btrans<<<dim3(1024/32,128),dim3(32,8),0,stream>>>(encT, encRow, 1024);

  gemm_k<3><<<dim3(1,32),256,0,stream>>>(encRow, UaB, nullptr, Uenc, nullptr, 128, 1024, 128);
  gemm_k<3><<<dim3(12,32),256,0,stream>>>(encRow, WxeT, bi_d, gxeR, nullptr, 1536, 1024, 1536);
  gemm_k<1><<<dim3(12,32),256,0,stream>>>(encRow, WxcT, nullptr, encxT1, nullptr, 1536, 1024, 1536);
  etrans<<<1536,256,0,stream>>>(encxT1, encx);

  dec_init<<<32,256,0,stream>>>(hfin, hband_d);

  dec_scan<<<48,512,0,stream>>>(gxeR, encx, WhdT, br_d, WaB, Uenc, V_a,
                                hfin, hband_d, GHband, decRow, hflag, gflag);

  gemm_k<2><<<dim3(NCB,32),256,0,stream>>>(decRow, WoT, bo, d_out, psum, NV, 512, NV);

  scale_rows<<<4096,256,0,stream>>>((float*)d_out, psum, NV, 2*NCB);
}